// Round 9
// baseline (712.083 us; speedup 1.0000x reference)
//
#include <hip/hip_runtime.h>
#include <hip/hip_bf16.h>
#include <stdint.h>

// Problem constants (fixed by reference)
#define TOKENS_C 8192
#define NIN_C    4096
#define NOUT_C   4096
#define GROUP_C  128
#define QZERO_C  8

typedef float   f32x4  __attribute__((ext_vector_type(4)));
typedef int     i32x4  __attribute__((ext_vector_type(4)));

#define GAS __attribute__((address_space(1)))
#define LAS __attribute__((address_space(3)))

__device__ __forceinline__ void gload16(const void* g, void* l) {
  __builtin_amdgcn_global_load_lds((const GAS void*)g, (LAS void*)l, 16, 0, 0);
}

// ---------------- pass 1a: per-token quantize x -> i8 + sx -------------------
__global__ __launch_bounds__(256) void quant_x_kernel(
    const float* __restrict__ x, char* __restrict__ x8, float* __restrict__ sx)
{
  const int t   = blockIdx.x;
  const int tid = threadIdx.x;
  const float* xr = x + (size_t)t * NIN_C;
  f32x4 v[4];
#pragma unroll
  for (int r = 0; r < 4; ++r) v[r] = *(const f32x4*)(xr + tid * 16 + r * 4);
  float m = 0.f;
#pragma unroll
  for (int r = 0; r < 4; ++r)
#pragma unroll
    for (int e = 0; e < 4; ++e) m = fmaxf(m, fabsf(v[r][e]));
#pragma unroll
  for (int off = 32; off >= 1; off >>= 1) m = fmaxf(m, __shfl_xor(m, off));
  __shared__ float wmax[4];
  if ((tid & 63) == 0) wmax[tid >> 6] = m;
  __syncthreads();
  m = fmaxf(fmaxf(wmax[0], wmax[1]), fmaxf(wmax[2], wmax[3]));
  m = fmaxf(m, 1e-20f);
  const float inv = 127.0f / m;
  if (tid == 0) sx[t] = m / 127.0f;
  i32x4 o;
#pragma unroll
  for (int r = 0; r < 4; ++r) {
    int q0 = (int)rintf(v[r][0] * inv), q1 = (int)rintf(v[r][1] * inv);
    int q2 = (int)rintf(v[r][2] * inv), q3 = (int)rintf(v[r][3] * inv);
    o[r] = (q0 & 255) | ((q1 & 255) << 8) | ((q2 & 255) << 16) | ((q3 & 255) << 24);
  }
  *(i32x4*)(x8 + (size_t)t * NIN_C + tid * 16) = o;
}

// ---------------- pass 1b: repack qweight (int32 codes) -> i8 (q-8) ----------
__global__ __launch_bounds__(256) void repack_w_kernel(
    const int* __restrict__ qw, char* __restrict__ w8)
{
  const size_t base = ((size_t)blockIdx.x * 256 + threadIdx.x) * 16;
  i32x4 o;
#pragma unroll
  for (int r = 0; r < 4; ++r) {
    i32x4 q = *(const i32x4*)(qw + base + r * 4);
    o[r] = ((q[0] - QZERO_C) & 255) | (((q[1] - QZERO_C) & 255) << 8) |
           (((q[2] - QZERO_C) & 255) << 16) | (((q[3] - QZERO_C) & 255) << 24);
  }
  *(i32x4*)(w8 + base) = o;
}

// ---------------- pass 1c: transpose scales [NOUT][32] -> sT[32][NOUT] -------
__global__ __launch_bounds__(256) void tsc_kernel(
    const float* __restrict__ sc, float* __restrict__ sT)
{
  const int id = blockIdx.x * 256 + threadIdx.x;   // over 32*4096
  const int o = id & (NOUT_C - 1), g = id >> 12;
  sT[id] = sc[o * (NIN_C / GROUP_C) + g];
}

// ---------------- pass 2: i8 GEMM, C[t,o] = sx[t] * sum_g sT[g][o]*dot_g -----
// 256x256 tile, BK=128 (= one GPTQ group), 512 threads (8 waves 2Mx4N),
// dbuf LDS 128KB, R7's 2-barrier/tile skeleton, 0-conflict XOR swizzle,
// counted vmcnt(4) never 0 in main loop. Per tile: i32 group-dot via
// mfma_i32_16x16x64_i8 (2 per output frag), then facc += cvt(i32)*s[o,g].
// waves_per_eu(2,2): LDS already caps at 1 block/CU (= 2 waves/SIMD); this
// pins the register budget at 256 so facc[8][4] (128 VGPR) does NOT spill
// (R8: RA targeted 128 regs -> 1.6GB scratch writes, MfmaUtil 7%).
#define BM 256
#define BN 256
#define BKB 128                    // K bytes per tile (i8)
#define NT (NIN_C / BKB)           // 32 tiles

__global__ __launch_bounds__(512) __attribute__((amdgpu_waves_per_eu(2, 2)))
void gemm_i8_kernel(
    const char* __restrict__ A,    // x8 [M][K] i8
    const char* __restrict__ B,    // w8 [N][K] i8
    const float* __restrict__ sTg, // [32][NOUT]
    const float* __restrict__ sx,  // [M]
    float* __restrict__ C)         // [M][N] f32
{
  constexpr int N = NOUT_C, KB = NIN_C;  // K bytes per row
  // A: parity p at smem + p*32768 ; B: parity p at smem + 65536 + p*32768
  __shared__ char smem[131072];

  const int tid  = threadIdx.x;
  const int lane = tid & 63;
  const int wid  = tid >> 6;
  const int wm   = wid >> 2;       // 0..1 -> 128 rows of C
  const int wn   = wid & 3;        // 0..3 -> 64 cols of C
  const int bm   = blockIdx.x;
  const int bn   = blockIdx.y;

  const int frow  = lane & 15;
  const int klane = lane >> 4;     // 0..3
  const int swr   = lane & 7;      // row&7 for fragment rows (row%8==lane%8)

  // staging: tile-operand 256 rows x 128B; halves h (128 rows, 16KB, 2 gloads)
  // thread -> slot wid*2+l (8 rows x 128B); row = h*128+slot*8+(lane>>3),
  // granule lane&7 pre-swizzled with involution g ^= (row&7)==(lane>>3).
  const int cswz = (((lane & 7) ^ (lane >> 3)) << 4);
  uint32_t aso[2][2], bso[2][2];   // u32 byte offsets (arrays < 4GB)
#pragma unroll
  for (int h = 0; h < 2; ++h)
#pragma unroll
    for (int l = 0; l < 2; ++l) {
      const int r = h * 128 + (wid * 2 + l) * 8 + (lane >> 3);
      aso[h][l] = (uint32_t)((bm * BM + r) * KB + cswz);
      bso[h][l] = (uint32_t)((bn * BN + r) * KB + cswz);
    }
  const int sdst = wid * 2048 + (lane << 4);

#define STG_A(tt, h) { char* d_ = smem + (((tt) & 1) << 15) + ((h) << 14) + sdst; \
    gload16(A + (int64_t)aso[h][0] + (tt) * BKB, d_);                             \
    gload16(A + (int64_t)aso[h][1] + (tt) * BKB, d_ + 1024); }
#define STG_B(tt, h) { char* d_ = smem + 65536 + (((tt) & 1) << 15) + ((h) << 14) + sdst; \
    gload16(B + (int64_t)bso[h][0] + (tt) * BKB, d_);                             \
    gload16(B + (int64_t)bso[h][1] + (tt) * BKB, d_ + 1024); }

  const int ccol0 = bn * BN + wn * 64;

#define LD_S(dst, g)                                                           \
  _Pragma("unroll")                                                            \
  for (int j_ = 0; j_ < 4; ++j_)                                               \
    dst[j_] = sTg[(size_t)(g) * NOUT_C + ccol0 + j_ * 16 + frow];

  // fragment reads (i8 16x16x64: lane holds 16 contiguous k at k0=klane*16;
  // granule = (ks*4+klane) ^ (row&7), row%8 == lane%8)
#define ARD(Ad, ii, ks) (*(const i32x4*)((Ad) + ((ii) * 16 + frow) * 128 +     \
                         (((((ks) << 2) | klane) ^ swr) << 4)))
  i32x4 bf[4][2];
#define BRD_ALL(Bd)                                                            \
  _Pragma("unroll")                                                            \
  for (int j_ = 0; j_ < 4; ++j_) {                                             \
    bf[j_][0] = *(const i32x4*)((Bd) + (j_ * 16 + frow) * 128 + ((klane ^ swr) << 4)); \
    bf[j_][1] = *(const i32x4*)((Bd) + (j_ * 16 + frow) * 128 + (((4 | klane) ^ swr) << 4)); }

  f32x4 facc[8][4] = {};
  const i32x4 zq = {0, 0, 0, 0};

#define MFI(a_, b_, c_) __builtin_amdgcn_mfma_i32_16x16x64_i8(a_, b_, c_, 0, 0, 0)
#define SC_APPLY(ii, jj, tv, scur)                                             \
  { f32x4 tf_;                                                                 \
    tf_[0] = (float)(tv)[0]; tf_[1] = (float)(tv)[1];                          \
    tf_[2] = (float)(tv)[2]; tf_[3] = (float)(tv)[3];                          \
    facc[ii][jj] += tf_ * (scur)[jj]; }
#define DO_I(ii, Ad, scur)                                                     \
  { i32x4 ak0_ = ARD(Ad, ii, 0), ak1_ = ARD(Ad, ii, 1);                        \
    i32x4 t0_, t1_, t2_, t3_;                                                  \
    __builtin_amdgcn_s_setprio(1);                                             \
    t0_ = MFI(ak0_, bf[0][0], zq); t0_ = MFI(ak1_, bf[0][1], t0_);             \
    t1_ = MFI(ak0_, bf[1][0], zq); t1_ = MFI(ak1_, bf[1][1], t1_);             \
    t2_ = MFI(ak0_, bf[2][0], zq); t2_ = MFI(ak1_, bf[2][1], t2_);             \
    t3_ = MFI(ak0_, bf[3][0], zq); t3_ = MFI(ak1_, bf[3][1], t3_);             \
    __builtin_amdgcn_s_setprio(0);                                             \
    SC_APPLY(ii, 0, t0_, scur); SC_APPLY(ii, 1, t1_, scur);                    \
    SC_APPLY(ii, 2, t2_, scur); SC_APPLY(ii, 3, t3_, scur); }

#define BAR __builtin_amdgcn_s_barrier()
#define WAITV(n) asm volatile("s_waitcnt vmcnt(" #n ")" ::: "memory")
#define SBAR0 __builtin_amdgcn_sched_barrier(0)

  float sA[4], sB[4];

  // ---- prologue: s(0) loads FIRST (oldest in queue), then A(0),B(0),B(1) ---
  LD_S(sA, 0);
  SBAR0;
  STG_A(0, 0); STG_A(0, 1);
  STG_B(0, 0); STG_B(0, 1);
  STG_B(1, 0); STG_B(1, 1);
  WAITV(4);                 // 16 issued; retire s0+A0+B0, keep B(1) flying
  BAR; SBAR0;

  // One tile: ph1-3 barrier-free, mid-BAR, ph4, counted WAITV, end-BAR.
  // in-flight ledger entering tile t: [B(t+1)]=4. +s(t+1)+A(t+1)+B(t+2)=16;
  // WAITV(4) retires s+A+B(t+1), keeps B(t+2). Never 0 in main loop.
#define TILE(tt, par, scur, snxt, DO_SN, DO_SA, DO_SB, WVN)                    \
  {                                                                            \
    const char* Ad_ = smem + (par) * 32768 + wm * 16384;                       \
    const char* Bd_ = smem + 65536 + (par) * 32768 + wn * 8192;                \
    if (DO_SN) { LD_S(snxt, (tt) + 1); }                                       \
    BRD_ALL(Bd_);                                                              \
    if (DO_SA) { STG_A((tt) + 1, 0); }                                         \
    DO_I(0, Ad_, scur); DO_I(1, Ad_, scur);                                    \
    if (DO_SA) { STG_A((tt) + 1, 1); }                                         \
    DO_I(2, Ad_, scur); DO_I(3, Ad_, scur);                                    \
    DO_I(4, Ad_, scur); DO_I(5, Ad_, scur);                                    \
    SBAR0; BAR;                                                                \
    if (DO_SB) { STG_B((tt) + 2, 0); STG_B((tt) + 2, 1); }                     \
    DO_I(6, Ad_, scur); DO_I(7, Ad_, scur);                                    \
    WAITV(WVN); SBAR0; BAR;                                                    \
  }

  for (int t0 = 0; t0 < NT - 2; t0 += 2) {
    TILE(t0,     0, sA, sB, 1, 1, 1, 4);
    TILE(t0 + 1, 1, sB, sA, 1, 1, 1, 4);
  }
  // tile NT-2 = 30 (par 0): stage A(31) + s(31); no B-stage; full drain
  TILE(NT - 2, 0, sA, sB, 1, 1, 0, 0);
  // tile NT-1 = 31 (par 1): no stages, no barriers
  {
    const char* Ad_ = smem + 32768 + wm * 16384;
    const char* Bd_ = smem + 65536 + 32768 + wn * 8192;
    BRD_ALL(Bd_);
    DO_I(0, Ad_, sB); DO_I(1, Ad_, sB); DO_I(2, Ad_, sB); DO_I(3, Ad_, sB);
    DO_I(4, Ad_, sB); DO_I(5, Ad_, sB); DO_I(6, Ad_, sB); DO_I(7, Ad_, sB);
  }

  // ---- epilogue: C = sx[row] * facc. C/D: col=lane&15, row=(lane>>4)*4+r ---
  const int crow0 = bm * BM + wm * 128;
  const int r0 = (lane >> 4) << 2;
#pragma unroll
  for (int fi = 0; fi < 8; ++fi) {
    const f32x4 sxv = *(const f32x4*)(sx + crow0 + fi * 16 + r0);
#pragma unroll
    for (int j = 0; j < 4; ++j) {
      f32x4 v = facc[fi][j];
#pragma unroll
      for (int r = 0; r < 4; ++r)
        C[(int64_t)(crow0 + fi * 16 + r0 + r) * N + (ccol0 + j * 16 + frow)] =
            v[r] * sxv[r];
    }
  }
#undef STG_A
#undef STG_B
#undef LD_S
#undef ARD
#undef BRD_ALL
#undef MFI
#undef SC_APPLY
#undef DO_I
#undef TILE
#undef BAR
#undef WAITV
#undef SBAR0
}

// ---------------- fallback (only if ws too small): naive fp32 ---------------
__global__ __launch_bounds__(256) void naive_kernel(
    const float* __restrict__ x, const int* __restrict__ qw,
    const float* __restrict__ sc, float* __restrict__ out)
{
  const int64_t idx = (int64_t)blockIdx.x * 256 + threadIdx.x;
  const int tok = (int)(idx >> 12);
  const int o   = (int)(idx & 4095);
  const float* xr = x + (int64_t)tok * NIN_C;
  const int* qr = qw + (int64_t)o * NIN_C;
  float acc = 0.f;
  for (int g = 0; g < NIN_C / GROUP_C; ++g) {
    float s = sc[(o << 5) | g];
    float ga = 0.f;
#pragma unroll 4
    for (int i = g * GROUP_C; i < (g + 1) * GROUP_C; ++i)
      ga += xr[i] * (float)(qr[i] - QZERO_C);
    acc += s * ga;
  }
  out[idx] = acc;
}

extern "C" void kernel_launch(void* const* d_in, const int* in_sizes, int n_in,
                              void* d_out, int out_size, void* d_ws, size_t ws_size,
                              hipStream_t stream) {
  const float* x  = (const float*)d_in[0];
  const int*   qw = (const int*)d_in[1];
  const float* sc = (const float*)d_in[2];
  float* out = (float*)d_out;

  const size_t x8_bytes = (size_t)TOKENS_C * NIN_C;          // 32 MiB
  const size_t w8_bytes = (size_t)NOUT_C * NIN_C;            // 16 MiB
  const size_t sx_bytes = (size_t)TOKENS_C * sizeof(float);  // 32 KiB
  const size_t sT_bytes = (size_t)(NIN_C / GROUP_C) * NOUT_C * sizeof(float);

  if (ws_size < x8_bytes + w8_bytes + sx_bytes + sT_bytes) {
    const int64_t total = (int64_t)TOKENS_C * NOUT_C;
    naive_kernel<<<(int)(total / 256), 256, 0, stream>>>(x, qw, sc, out);
    return;
  }

  char*  x8 = (char*)d_ws;
  char*  w8 = (char*)d_ws + x8_bytes;
  float* sx = (float*)((char*)d_ws + x8_bytes + w8_bytes);
  float* sT = (float*)((char*)d_ws + x8_bytes + w8_bytes + sx_bytes);

  quant_x_kernel<<<TOKENS_C, 256, 0, stream>>>(x, x8, sx);
  repack_w_kernel<<<(int)(w8_bytes / 16 / 256), 256, 0, stream>>>(qw, w8);
  tsc_kernel<<<(int)((NIN_C / GROUP_C) * NOUT_C / 256), 256, 0, stream>>>(sc, sT);
  {
    dim3 grid(TOKENS_C / BM, NOUT_C / BN);   // 32 x 16 = 512 wg
    gemm_i8_kernel<<<grid, 512, 0, stream>>>(x8, w8, sT, sx, out);
  }
}

// Round 10
// 349.375 us; speedup vs baseline: 2.0382x; 2.0382x over previous
//
#include <hip/hip_runtime.h>
#include <hip/hip_bf16.h>
#include <stdint.h>

// Problem constants (fixed by reference)
#define TOKENS_C 8192
#define NIN_C    4096
#define NOUT_C   4096
#define GROUP_C  128
#define QZERO_C  8

typedef float   f32x4  __attribute__((ext_vector_type(4)));
typedef int     i32x4  __attribute__((ext_vector_type(4)));

#define GAS __attribute__((address_space(1)))
#define LAS __attribute__((address_space(3)))

__device__ __forceinline__ void gload16(const void* g, void* l) {
  __builtin_amdgcn_global_load_lds((const GAS void*)g, (LAS void*)l, 16, 0, 0);
}

// ---------------- pass 1a: per-token quantize x -> i8 + sx -------------------
__global__ __launch_bounds__(256) void quant_x_kernel(
    const float* __restrict__ x, char* __restrict__ x8, float* __restrict__ sx)
{
  const int t   = blockIdx.x;
  const int tid = threadIdx.x;
  const float* xr = x + (size_t)t * NIN_C;
  f32x4 v[4];
#pragma unroll
  for (int r = 0; r < 4; ++r) v[r] = *(const f32x4*)(xr + tid * 16 + r * 4);
  float m = 0.f;
#pragma unroll
  for (int r = 0; r < 4; ++r)
#pragma unroll
    for (int e = 0; e < 4; ++e) m = fmaxf(m, fabsf(v[r][e]));
#pragma unroll
  for (int off = 32; off >= 1; off >>= 1) m = fmaxf(m, __shfl_xor(m, off));
  __shared__ float wmax[4];
  if ((tid & 63) == 0) wmax[tid >> 6] = m;
  __syncthreads();
  m = fmaxf(fmaxf(wmax[0], wmax[1]), fmaxf(wmax[2], wmax[3]));
  m = fmaxf(m, 1e-20f);
  const float inv = 127.0f / m;
  if (tid == 0) sx[t] = m / 127.0f;
  i32x4 o;
#pragma unroll
  for (int r = 0; r < 4; ++r) {
    int q0 = (int)rintf(v[r][0] * inv), q1 = (int)rintf(v[r][1] * inv);
    int q2 = (int)rintf(v[r][2] * inv), q3 = (int)rintf(v[r][3] * inv);
    o[r] = (q0 & 255) | ((q1 & 255) << 8) | ((q2 & 255) << 16) | ((q3 & 255) << 24);
  }
  *(i32x4*)(x8 + (size_t)t * NIN_C + tid * 16) = o;
}

// ---------------- pass 1b: repack qweight (int32 codes) -> i8 (q-8) ----------
__global__ __launch_bounds__(256) void repack_w_kernel(
    const int* __restrict__ qw, char* __restrict__ w8)
{
  const size_t base = ((size_t)blockIdx.x * 256 + threadIdx.x) * 16;
  i32x4 o;
#pragma unroll
  for (int r = 0; r < 4; ++r) {
    i32x4 q = *(const i32x4*)(qw + base + r * 4);
    o[r] = ((q[0] - QZERO_C) & 255) | (((q[1] - QZERO_C) & 255) << 8) |
           (((q[2] - QZERO_C) & 255) << 16) | (((q[3] - QZERO_C) & 255) << 24);
  }
  *(i32x4*)(w8 + base) = o;
}

// ---------------- pass 1c: transpose scales [NOUT][32] -> sT[32][NOUT] -------
__global__ __launch_bounds__(256) void tsc_kernel(
    const float* __restrict__ sc, float* __restrict__ sT)
{
  const int id = blockIdx.x * 256 + threadIdx.x;   // over 32*4096
  const int o = id & (NOUT_C - 1), g = id >> 12;
  sT[id] = sc[o * (NIN_C / GROUP_C) + g];
}

// ---------------- pass 2: i8 GEMM ---------------------------------------------
// 256x256 tile, 1024 threads (16 waves 4Mx4N, wave tile 64x64 -> facc[4][4]=64
// arch VGPR, fits the 128/wave budget at 4 waves/SIMD — R8/R9 spilled because
// wave tile 128x64 needed 128 facc + operands). BKB=64 = MFMA K: fragment
// reads consume full 64B rows -> wave reads 1KB contiguous = conflict-free,
// NO swizzle anywhere; staging = 1 gload16/thread/operand, linear.
// 4-slot LDS ring (4 x 32KB = 128KB): compute slot t&3, stage tile t+3.
// ONE barrier per tile; counted WAITV (even tiles 8, odd 4; never 0).
// Scales sT[g][o] prefetched 2 tiles ahead through the same vmcnt queue.
#define BM 256
#define BN 256
#define BKB 64
#define NT (NIN_C / BKB)           // 64 tiles

__global__ __launch_bounds__(1024) void gemm_i8_kernel(
    const char* __restrict__ Ag,   // x8 [M][K] i8
    const char* __restrict__ Bg,   // w8 [N][K] i8
    const float* __restrict__ sTg, // [32][NOUT]
    const float* __restrict__ sx,  // [M]
    float* __restrict__ C)         // [M][N] f32
{
  constexpr int N = NOUT_C, KB = NIN_C;
  // slot s: A at s*32768, B at s*32768+16384
  __shared__ char smem[131072];

  const int tid  = threadIdx.x;
  const int lane = tid & 63;
  const int wid  = tid >> 6;       // 0..15
  const int wm   = wid >> 2;       // 0..3 -> 64 rows of C
  const int wn   = wid & 3;        // 0..3 -> 64 cols of C
  const int bm   = blockIdx.x;
  const int bn   = blockIdx.y;

  const int frow = lane & 15;
  const int koff = (lane >> 4) << 4;       // k-granule byte offset 0..48

  // staging: thread -> row tid>>2, 16B granule tid&3 (linear [256][64] tile)
  const uint32_t aoff = (uint32_t)((bm * BM + (tid >> 2)) * KB + (tid & 3) * 16);
  const uint32_t boff = (uint32_t)((bn * BN + (tid >> 2)) * KB + (tid & 3) * 16);
  const int sdst = tid * 16;

#define STG(tt, SW) { char* d_ = smem + (SW) * 32768 + sdst;                   \
    gload16(Ag + aoff + (uint32_t)(tt) * BKB, d_);                             \
    gload16(Bg + boff + (uint32_t)(tt) * BKB, d_ + 16384); }

  const int ccol0 = bn * BN + wn * 64;
  const int scoff = ccol0 + frow;
#define LD_S(dst, g)                                                           \
  _Pragma("unroll")                                                            \
  for (int j_ = 0; j_ < 4; ++j_)                                               \
    dst[j_] = sTg[(size_t)(g) * NOUT_C + scoff + j_ * 16];

  // fragment read bases (dense, conflict-free: wave covers 1KB contiguous)
  const int ard0 = (wm * 64 + frow) * 64 + koff;           // + ii*1024
  const int brd0 = (wn * 64 + frow) * 64 + koff + 16384;   // + j*1024

  f32x4 facc[4][4] = {};
  const i32x4 zq = {0, 0, 0, 0};

#define MFI(a_, b_, c_) __builtin_amdgcn_mfma_i32_16x16x64_i8(a_, b_, c_, 0, 0, 0)
#define APPLY(ii, jj, pv, scur)                                                \
  { f32x4 tf_;                                                                 \
    tf_[0] = (float)(pv)[0]; tf_[1] = (float)(pv)[1];                          \
    tf_[2] = (float)(pv)[2]; tf_[3] = (float)(pv)[3];                          \
    facc[ii][jj] += tf_ * (scur)[jj]; }
#define BAR __builtin_amdgcn_s_barrier()
#define WAITV(n) asm volatile("s_waitcnt vmcnt(" #n ")" ::: "memory")
#define SBAR0 __builtin_amdgcn_sched_barrier(0)

  // One tile: LD_S (even) -> STG(t+3) -> 4 bf reads -> 4x{ak read, 4 MFMA,
  // 4 apply} -> counted WAITV -> barrier. Ring slot (t+3)&3 was last read in
  // tile t-1, whose end barrier precedes this stage issue -> race-free.
#define TILE(tt, SLOT, scur, DO_LDS, snxt, gnxt, DO_STG, WVN)                  \
  {                                                                            \
    const char* As_ = smem + (SLOT) * 32768;                                   \
    const char* Bs_ = smem + (SLOT) * 32768;                                   \
    if (DO_LDS) { LD_S(snxt, gnxt); }                                          \
    if (DO_STG) { STG((tt) + 3, ((SLOT) + 3) & 3); }                           \
    i32x4 bf0 = *(const i32x4*)(Bs_ + brd0);                                   \
    i32x4 bf1 = *(const i32x4*)(Bs_ + brd0 + 1024);                            \
    i32x4 bf2 = *(const i32x4*)(Bs_ + brd0 + 2048);                            \
    i32x4 bf3 = *(const i32x4*)(Bs_ + brd0 + 3072);                            \
    _Pragma("unroll")                                                          \
    for (int ii = 0; ii < 4; ++ii) {                                           \
      i32x4 ak = *(const i32x4*)(As_ + ard0 + ii * 1024);                      \
      i32x4 p0, p1, p2, p3;                                                    \
      __builtin_amdgcn_s_setprio(1);                                           \
      p0 = MFI(ak, bf0, zq); p1 = MFI(ak, bf1, zq);                            \
      p2 = MFI(ak, bf2, zq); p3 = MFI(ak, bf3, zq);                            \
      __builtin_amdgcn_s_setprio(0);                                           \
      APPLY(ii, 0, p0, scur); APPLY(ii, 1, p1, scur);                          \
      APPLY(ii, 2, p2, scur); APPLY(ii, 3, p3, scur);                          \
    }                                                                          \
    WAITV(WVN); SBAR0; BAR;                                                    \
  }

  float sA[4], sB[4];

  // ---- prologue: s(0) first (oldest), then tiles 0,1,2 into slots 0,1,2 ----
  LD_S(sA, 0);
  SBAR0;
  STG(0, 0); STG(1, 1); STG(2, 2);
  WAITV(4);                 // queue 10 -> retire s0 + tile0 stages
  BAR; SBAR0;

  // ---- main loop: 4 tiles/iter (slots 0..3 compile-time since t0 % 4 == 0).
  // Tiles t0,t0+1 use sA=s(g0), load sB=s(g0+1); t0+2,t0+3 use sB, load
  // sA=s(g0+2). Ledger: even-tile end WAITV(8), odd-tile end WAITV(4).
  for (int t0 = 0; t0 < NT - 8; t0 += 4) {
    const int g0 = t0 >> 1;
    TILE(t0,     0, sA, 1, sB, g0 + 1, 1, 8);
    TILE(t0 + 1, 1, sA, 0, sB, 0,      1, 4);
    TILE(t0 + 2, 2, sB, 1, sA, g0 + 2, 1, 8);
    TILE(t0 + 3, 3, sB, 0, sA, 0,      1, 4);
  }
  // ---- peel tiles 56..63 (groups 28..31; sA holds s28 entering) ----
  TILE(56, 0, sA, 1, sB, 29, 1, 8);
  TILE(57, 1, sA, 0, sB, 0,  1, 4);
  TILE(58, 2, sB, 1, sA, 30, 1, 8);
  TILE(59, 3, sB, 0, sA, 0,  1, 4);
  TILE(60, 0, sA, 1, sB, 31, 1, 8);   // stages tile 63 (last)
  TILE(61, 1, sA, 0, sB, 0,  0, 2);   // retires tile-62 stage + s31
  TILE(62, 2, sB, 0, sA, 0,  0, 0);   // retires tile-63 stage
  TILE(63, 3, sB, 0, sA, 0,  0, 0);

  // ---- epilogue: C = sx[row] * facc. C/D: col=lane&15, row=(lane>>4)*4+r ---
  const int crow0 = bm * BM + wm * 64;
  const int r0 = (lane >> 4) << 2;
#pragma unroll
  for (int fi = 0; fi < 4; ++fi) {
    const f32x4 sxv = *(const f32x4*)(sx + crow0 + fi * 16 + r0);
#pragma unroll
    for (int j = 0; j < 4; ++j) {
      f32x4 v = facc[fi][j];
#pragma unroll
      for (int r = 0; r < 4; ++r)
        C[(int64_t)(crow0 + fi * 16 + r0 + r) * N + (ccol0 + j * 16 + frow)] =
            v[r] * sxv[r];
    }
  }
#undef STG
#undef LD_S
#undef MFI
#undef APPLY
#undef TILE
#undef BAR
#undef WAITV
#undef SBAR0
}

// ---------------- fallback (only if ws too small): naive fp32 ---------------
__global__ __launch_bounds__(256) void naive_kernel(
    const float* __restrict__ x, const int* __restrict__ qw,
    const float* __restrict__ sc, float* __restrict__ out)
{
  const int64_t idx = (int64_t)blockIdx.x * 256 + threadIdx.x;
  const int tok = (int)(idx >> 12);
  const int o   = (int)(idx & 4095);
  const float* xr = x + (int64_t)tok * NIN_C;
  const int* qr = qw + (int64_t)o * NIN_C;
  float acc = 0.f;
  for (int g = 0; g < NIN_C / GROUP_C; ++g) {
    float s = sc[(o << 5) | g];
    float ga = 0.f;
#pragma unroll 4
    for (int i = g * GROUP_C; i < (g + 1) * GROUP_C; ++i)
      ga += xr[i] * (float)(qr[i] - QZERO_C);
    acc += s * ga;
  }
  out[idx] = acc;
}

extern "C" void kernel_launch(void* const* d_in, const int* in_sizes, int n_in,
                              void* d_out, int out_size, void* d_ws, size_t ws_size,
                              hipStream_t stream) {
  const float* x  = (const float*)d_in[0];
  const int*   qw = (const int*)d_in[1];
  const float* sc = (const float*)d_in[2];
  float* out = (float*)d_out;

  const size_t x8_bytes = (size_t)TOKENS_C * NIN_C;          // 32 MiB
  const size_t w8_bytes = (size_t)NOUT_C * NIN_C;            // 16 MiB
  const size_t sx_bytes = (size_t)TOKENS_C * sizeof(float);  // 32 KiB
  const size_t sT_bytes = (size_t)(NIN_C / GROUP_C) * NOUT_C * sizeof(float);

  if (ws_size < x8_bytes + w8_bytes + sx_bytes + sT_bytes) {
    const int64_t total = (int64_t)TOKENS_C * NOUT_C;
    naive_kernel<<<(int)(total / 256), 256, 0, stream>>>(x, qw, sc, out);
    return;
  }

  char*  x8 = (char*)d_ws;
  char*  w8 = (char*)d_ws + x8_bytes;
  float* sx = (float*)((char*)d_ws + x8_bytes + w8_bytes);
  float* sT = (float*)((char*)d_ws + x8_bytes + w8_bytes + sx_bytes);

  quant_x_kernel<<<TOKENS_C, 256, 0, stream>>>(x, x8, sx);
  repack_w_kernel<<<(int)(w8_bytes / 16 / 256), 256, 0, stream>>>(qw, w8);
  tsc_kernel<<<(int)((NIN_C / GROUP_C) * NOUT_C / 256), 256, 0, stream>>>(sc, sT);
  {
    dim3 grid(TOKENS_C / BM, NOUT_C / BN);   // 32 x 16 = 512 wg
    gemm_i8_kernel<<<grid, 1024, 0, stream>>>(x8, w8, sT, sx, out);
  }
}

// Round 12
// 330.621 us; speedup vs baseline: 2.1538x; 1.0567x over previous
//
#include <hip/hip_runtime.h>
#include <hip/hip_bf16.h>
#include <stdint.h>

// Problem constants (fixed by reference)
#define TOKENS_C 8192
#define NIN_C    4096
#define NOUT_C   4096
#define GROUP_C  128
#define QZERO_C  8

typedef float   f32x4  __attribute__((ext_vector_type(4)));
typedef int     i32x4  __attribute__((ext_vector_type(4)));

#define GAS __attribute__((address_space(1)))
#define LAS __attribute__((address_space(3)))

__device__ __forceinline__ void gload16(const void* g, void* l) {
  __builtin_amdgcn_global_load_lds((const GAS void*)g, (LAS void*)l, 16, 0, 0);
}

// ---------------- pass 1a: per-token quantize x -> i8 + sx -------------------
__global__ __launch_bounds__(256) void quant_x_kernel(
    const float* __restrict__ x, char* __restrict__ x8, float* __restrict__ sx)
{
  const int t   = blockIdx.x;
  const int tid = threadIdx.x;
  const float* xr = x + (size_t)t * NIN_C;
  f32x4 v[4];
#pragma unroll
  for (int r = 0; r < 4; ++r) v[r] = *(const f32x4*)(xr + tid * 16 + r * 4);
  float m = 0.f;
#pragma unroll
  for (int r = 0; r < 4; ++r)
#pragma unroll
    for (int e = 0; e < 4; ++e) m = fmaxf(m, fabsf(v[r][e]));
#pragma unroll
  for (int off = 32; off >= 1; off >>= 1) m = fmaxf(m, __shfl_xor(m, off));
  __shared__ float wmax[4];
  if ((tid & 63) == 0) wmax[tid >> 6] = m;
  __syncthreads();
  m = fmaxf(fmaxf(wmax[0], wmax[1]), fmaxf(wmax[2], wmax[3]));
  m = fmaxf(m, 1e-20f);
  const float inv = 127.0f / m;
  if (tid == 0) sx[t] = m / 127.0f;
  i32x4 o;
#pragma unroll
  for (int r = 0; r < 4; ++r) {
    int q0 = (int)rintf(v[r][0] * inv), q1 = (int)rintf(v[r][1] * inv);
    int q2 = (int)rintf(v[r][2] * inv), q3 = (int)rintf(v[r][3] * inv);
    o[r] = (q0 & 255) | ((q1 & 255) << 8) | ((q2 & 255) << 16) | ((q3 & 255) << 24);
  }
  *(i32x4*)(x8 + (size_t)t * NIN_C + tid * 16) = o;
}

// ---------------- pass 1b: repack qweight (int32 codes) -> i8 (q-8) ----------
__global__ __launch_bounds__(256) void repack_w_kernel(
    const int* __restrict__ qw, char* __restrict__ w8)
{
  const size_t base = ((size_t)blockIdx.x * 256 + threadIdx.x) * 16;
  i32x4 o;
#pragma unroll
  for (int r = 0; r < 4; ++r) {
    i32x4 q = *(const i32x4*)(qw + base + r * 4);
    o[r] = ((q[0] - QZERO_C) & 255) | (((q[1] - QZERO_C) & 255) << 8) |
           (((q[2] - QZERO_C) & 255) << 16) | (((q[3] - QZERO_C) & 255) << 24);
  }
  *(i32x4*)(w8 + base) = o;
}

// ---------------- pass 1c: transpose scales [NOUT][32] -> sT[32][NOUT] -------
__global__ __launch_bounds__(256) void tsc_kernel(
    const float* __restrict__ sc, float* __restrict__ sT)
{
  const int id = blockIdx.x * 256 + threadIdx.x;   // over 32*4096
  const int o = id & (NOUT_C - 1), g = id >> 12;
  sT[id] = sc[o * (NIN_C / GROUP_C) + g];
}

// ---------------- pass 2: i8 GEMM ---------------------------------------------
// R10 structure (256x256 tile, 16 waves 4Mx4N wave-tile 64x64 = facc[4][4] 64
// VGPR no-spill, 4-slot 32KB LDS ring, 1 barrier/tile, counted WAITV) with:
// (1) LDS swizzle for 64B rows: granule g -> g ^ ((row>>1)&3), source-
//     preswizzled (dest linear), same XOR on fragment reads. Fixes R10's
//     8-way conflict (1.68e7).
// (2) transposed epilogue via LDS with __syncthreads() FENCE between scatter
//     and readback: R11 omitted the fence; the scalar-float scatter and f32x4
//     readback have different TBAA types, so the compiler may reorder the
//     wave-local LDS RAW/WAR -> garbage (absmax 25). __syncthreads is a full
//     compiler memory fence + lgkmcnt(0) + barrier; uniform control flow.
#define BM 256
#define BN 256
#define BKB 64
#define NT (NIN_C / BKB)           // 64 tiles

__global__ __launch_bounds__(1024) void gemm_i8_kernel(
    const char* __restrict__ Ag,   // x8 [M][K] i8
    const char* __restrict__ Bg,   // w8 [N][K] i8
    const float* __restrict__ sTg, // [32][NOUT]
    const float* __restrict__ sx,  // [M]
    float* __restrict__ C)         // [M][N] f32
{
  constexpr int N = NOUT_C, KB = NIN_C;
  // slot s: A at s*32768, B at s*32768+16384
  __shared__ char smem[131072];

  const int tid  = threadIdx.x;
  const int lane = tid & 63;
  const int wid  = tid >> 6;       // 0..15
  const int wm   = wid >> 2;       // 0..3 -> 64 rows of C
  const int wn   = wid & 3;        // 0..3 -> 64 cols of C
  const int bm   = blockIdx.x;
  const int bn   = blockIdx.y;

  const int frow  = lane & 15;
  const int klane = lane >> 4;     // 0..3

  // staging: thread -> LDS row tid>>2, granule tid&3 (dest LINEAR);
  // source granule pre-swizzled: (tid&3) ^ ((tid>>3)&3)  [= g ^ ((row>>1)&3)]
  const int gsrc = ((tid & 3) ^ ((tid >> 3) & 3)) * 16;
  const uint32_t aoff = (uint32_t)((bm * BM + (tid >> 2)) * KB + gsrc);
  const uint32_t boff = (uint32_t)((bn * BN + (tid >> 2)) * KB + gsrc);
  const int sdst = tid * 16;

#define STG(tt, SW) { char* d_ = smem + (SW) * 32768 + sdst;                   \
    gload16(Ag + aoff + (uint32_t)(tt) * BKB, d_);                             \
    gload16(Bg + boff + (uint32_t)(tt) * BKB, d_ + 16384); }

  const int ccol0 = bn * BN + wn * 64;
  const int scoff = ccol0 + frow;
#define LD_S(dst, g)                                                           \
  _Pragma("unroll")                                                            \
  for (int j_ = 0; j_ < 4; ++j_)                                               \
    dst[j_] = sTg[(size_t)(g) * NOUT_C + scoff + j_ * 16];

  // fragment read bases with matching XOR swizzle (row%4 bits = frow%4)
  const int kswz = (klane ^ ((frow >> 1) & 3)) << 4;
  const int ard0 = (wm * 64 + frow) * 64 + kswz;           // + ii*1024
  const int brd0 = (wn * 64 + frow) * 64 + kswz + 16384;   // + j*1024

  f32x4 facc[4][4] = {};
  const i32x4 zq = {0, 0, 0, 0};

#define MFI(a_, b_, c_) __builtin_amdgcn_mfma_i32_16x16x64_i8(a_, b_, c_, 0, 0, 0)
#define APPLY(ii, jj, pv, scur)                                                \
  { f32x4 tf_;                                                                 \
    tf_[0] = (float)(pv)[0]; tf_[1] = (float)(pv)[1];                          \
    tf_[2] = (float)(pv)[2]; tf_[3] = (float)(pv)[3];                          \
    facc[ii][jj] += tf_ * (scur)[jj]; }
#define BAR __builtin_amdgcn_s_barrier()
#define WAITV(n) asm volatile("s_waitcnt vmcnt(" #n ")" ::: "memory")
#define SBAR0 __builtin_amdgcn_sched_barrier(0)

  // One tile: LD_S (even) -> STG(t+3) -> 4 bf reads -> 4x{ak read, 4 MFMA,
  // 4 apply} -> counted WAITV -> barrier. Ring slot (t+3)&3 was last read in
  // tile t-1, whose end barrier precedes this stage issue -> race-free.
#define TILE(tt, SLOT, scur, DO_LDS, snxt, gnxt, DO_STG, WVN)                  \
  {                                                                            \
    const char* As_ = smem + (SLOT) * 32768;                                   \
    const char* Bs_ = smem + (SLOT) * 32768;                                   \
    if (DO_LDS) { LD_S(snxt, gnxt); }                                          \
    if (DO_STG) { STG((tt) + 3, ((SLOT) + 3) & 3); }                           \
    i32x4 bf0 = *(const i32x4*)(Bs_ + brd0);                                   \
    i32x4 bf1 = *(const i32x4*)(Bs_ + brd0 + 1024);                            \
    i32x4 bf2 = *(const i32x4*)(Bs_ + brd0 + 2048);                            \
    i32x4 bf3 = *(const i32x4*)(Bs_ + brd0 + 3072);                            \
    _Pragma("unroll")                                                          \
    for (int ii = 0; ii < 4; ++ii) {                                           \
      i32x4 ak = *(const i32x4*)(As_ + ard0 + ii * 1024);                      \
      i32x4 p0, p1, p2, p3;                                                    \
      __builtin_amdgcn_s_setprio(1);                                           \
      p0 = MFI(ak, bf0, zq); p1 = MFI(ak, bf1, zq);                            \
      p2 = MFI(ak, bf2, zq); p3 = MFI(ak, bf3, zq);                            \
      __builtin_amdgcn_s_setprio(0);                                           \
      APPLY(ii, 0, p0, scur); APPLY(ii, 1, p1, scur);                          \
      APPLY(ii, 2, p2, scur); APPLY(ii, 3, p3, scur);                          \
    }                                                                          \
    WAITV(WVN); SBAR0; BAR;                                                    \
  }

  float sA[4], sB[4];

  // ---- prologue: s(0) first (oldest), then tiles 0,1,2 into slots 0,1,2 ----
  LD_S(sA, 0);
  SBAR0;
  STG(0, 0); STG(1, 1); STG(2, 2);
  WAITV(4);                 // queue 10 -> retire s0 + tile0 stages
  BAR; SBAR0;

  // ---- main loop: 4 tiles/iter (slots 0..3 compile-time since t0 % 4 == 0).
  // Tiles t0,t0+1 use sA=s(g0), load sB=s(g0+1); t0+2,t0+3 use sB, load
  // sA=s(g0+2). Ledger: even-tile end WAITV(8), odd-tile end WAITV(4).
  for (int t0 = 0; t0 < NT - 8; t0 += 4) {
    const int g0 = t0 >> 1;
    TILE(t0,     0, sA, 1, sB, g0 + 1, 1, 8);
    TILE(t0 + 1, 1, sA, 0, sB, 0,      1, 4);
    TILE(t0 + 2, 2, sB, 1, sA, g0 + 2, 1, 8);
    TILE(t0 + 3, 3, sB, 0, sA, 0,      1, 4);
  }
  // ---- peel tiles 56..63 (groups 28..31; sA holds s28 entering) ----
  TILE(56, 0, sA, 1, sB, 29, 1, 8);
  TILE(57, 1, sA, 0, sB, 0,  1, 4);
  TILE(58, 2, sB, 1, sA, 30, 1, 8);
  TILE(59, 3, sB, 0, sA, 0,  1, 4);
  TILE(60, 0, sA, 1, sB, 31, 1, 8);   // stages tile 63 (last)
  TILE(61, 1, sA, 0, sB, 0,  0, 2);   // retires tile-62 stage + s31
  TILE(62, 2, sB, 0, sA, 0,  0, 0);   // retires tile-63 stage
  TILE(63, 3, sB, 0, sA, 0,  0, 0);

  // ---- epilogue: transposed through LDS (smem free after final barrier).
  // Per fi: wave scatters its 16x64 f32 block (sx pre-applied) into a private
  // 4KB region (double-buffered on fi parity), __syncthreads (compiler fence
  // + lgkmcnt(0): orders the mixed-type LDS RAW; R11's missing fence was the
  // correctness bug), then reads back row-major and stores 256B-contiguous
  // runs to C (fixes R10's 4x write amplification).
  const int crow0 = bm * BM + wm * 64;
  const int r0 = klane << 2;
  char* const wb0 = smem + wid * 4096;
  char* const wb1 = smem + 65536 + wid * 4096;
#pragma unroll
  for (int fi = 0; fi < 4; ++fi) {
    char* wb = (fi & 1) ? wb1 : wb0;
    const f32x4 sxv = *(const f32x4*)(sx + crow0 + fi * 16 + r0);
#pragma unroll
    for (int j = 0; j < 4; ++j) {
      f32x4 v = facc[fi][j];
#pragma unroll
      for (int r = 0; r < 4; ++r)
        *(float*)(wb + (r0 + r) * 256 + (j * 16 + frow) * 4) = v[r] * sxv[r];
    }
    __syncthreads();   // fence: scatter (above) before readback (below);
                       // also orders fi's readback before fi+2's scatter
#pragma unroll
    for (int sub = 0; sub < 4; ++sub) {
      const int row16 = klane + sub * 4;
      f32x4 v = *(const f32x4*)(wb + row16 * 256 + frow * 16);
      *(f32x4*)(C + (int64_t)(crow0 + fi * 16 + row16) * N + ccol0 + frow * 4) = v;
    }
  }
#undef STG
#undef LD_S
#undef MFI
#undef APPLY
#undef TILE
#undef BAR
#undef WAITV
#undef SBAR0
}

// ---------------- fallback (only if ws too small): naive fp32 ---------------
__global__ __launch_bounds__(256) void naive_kernel(
    const float* __restrict__ x, const int* __restrict__ qw,
    const float* __restrict__ sc, float* __restrict__ out)
{
  const int64_t idx = (int64_t)blockIdx.x * 256 + threadIdx.x;
  const int tok = (int)(idx >> 12);
  const int o   = (int)(idx & 4095);
  const float* xr = x + (int64_t)tok * NIN_C;
  const int* qr = qw + (int64_t)o * NIN_C;
  float acc = 0.f;
  for (int g = 0; g < NIN_C / GROUP_C; ++g) {
    float s = sc[(o << 5) | g];
    float ga = 0.f;
#pragma unroll 4
    for (int i = g * GROUP_C; i < (g + 1) * GROUP_C; ++i)
      ga += xr[i] * (float)(qr[i] - QZERO_C);
    acc += s * ga;
  }
  out[idx] = acc;
}

extern "C" void kernel_launch(void* const* d_in, const int* in_sizes, int n_in,
                              void* d_out, int out_size, void* d_ws, size_t ws_size,
                              hipStream_t stream) {
  const float* x  = (const float*)d_in[0];
  const int*   qw = (const int*)d_in[1];
  const float* sc = (const float*)d_in[2];
  float* out = (float*)d_out;

  const size_t x8_bytes = (size_t)TOKENS_C * NIN_C;          // 32 MiB
  const size_t w8_bytes = (size_t)NOUT_C * NIN_C;            // 16 MiB
  const size_t sx_bytes = (size_t)TOKENS_C * sizeof(float);  // 32 KiB
  const size_t sT_bytes = (size_t)(NIN_C / GROUP_C) * NOUT_C * sizeof(float);

  if (ws_size < x8_bytes + w8_bytes + sx_bytes + sT_bytes) {
    const int64_t total = (int64_t)TOKENS_C * NOUT_C;
    naive_kernel<<<(int)(total / 256), 256, 0, stream>>>(x, qw, sc, out);
    return;
  }

  char*  x8 = (char*)d_ws;
  char*  w8 = (char*)d_ws + x8_bytes;
  float* sx = (float*)((char*)d_ws + x8_bytes + w8_bytes);
  float* sT = (float*)((char*)d_ws + x8_bytes + w8_bytes + sx_bytes);

  quant_x_kernel<<<TOKENS_C, 256, 0, stream>>>(x, x8, sx);
  repack_w_kernel<<<(int)(w8_bytes / 16 / 256), 256, 0, stream>>>(qw, w8);
  tsc_kernel<<<(int)((NIN_C / GROUP_C) * NOUT_C / 256), 256, 0, stream>>>(sc, sT);
  {
    dim3 grid(TOKENS_C / BM, NOUT_C / BN);   // 32 x 16 = 512 wg
    gemm_i8_kernel<<<grid, 1024, 0, stream>>>(x8, w8, sT, sx, out);
  }
}

// Round 13
// 280.452 us; speedup vs baseline: 2.5391x; 1.1789x over previous
//
#include <hip/hip_runtime.h>
#include <hip/hip_bf16.h>
#include <stdint.h>

// Problem constants (fixed by reference)
#define TOKENS_C 8192
#define NIN_C    4096
#define NOUT_C   4096
#define GROUP_C  128
#define QZERO_C  8

typedef float   f32x4  __attribute__((ext_vector_type(4)));
typedef int     i32x4  __attribute__((ext_vector_type(4)));

#define GAS __attribute__((address_space(1)))
#define LAS __attribute__((address_space(3)))

__device__ __forceinline__ void gload16(const void* g, void* l) {
  __builtin_amdgcn_global_load_lds((const GAS void*)g, (LAS void*)l, 16, 0, 0);
}

// ---------------- pass 1a: per-token quantize x -> i8 + sx -------------------
__global__ __launch_bounds__(256) void quant_x_kernel(
    const float* __restrict__ x, char* __restrict__ x8, float* __restrict__ sx)
{
  const int t   = blockIdx.x;
  const int tid = threadIdx.x;
  const float* xr = x + (size_t)t * NIN_C;
  f32x4 v[4];
#pragma unroll
  for (int r = 0; r < 4; ++r) v[r] = *(const f32x4*)(xr + tid * 16 + r * 4);
  float m = 0.f;
#pragma unroll
  for (int r = 0; r < 4; ++r)
#pragma unroll
    for (int e = 0; e < 4; ++e) m = fmaxf(m, fabsf(v[r][e]));
#pragma unroll
  for (int off = 32; off >= 1; off >>= 1) m = fmaxf(m, __shfl_xor(m, off));
  __shared__ float wmax[4];
  if ((tid & 63) == 0) wmax[tid >> 6] = m;
  __syncthreads();
  m = fmaxf(fmaxf(wmax[0], wmax[1]), fmaxf(wmax[2], wmax[3]));
  m = fmaxf(m, 1e-20f);
  const float inv = 127.0f / m;
  if (tid == 0) sx[t] = m / 127.0f;
  i32x4 o;
#pragma unroll
  for (int r = 0; r < 4; ++r) {
    int q0 = (int)rintf(v[r][0] * inv), q1 = (int)rintf(v[r][1] * inv);
    int q2 = (int)rintf(v[r][2] * inv), q3 = (int)rintf(v[r][3] * inv);
    o[r] = (q0 & 255) | ((q1 & 255) << 8) | ((q2 & 255) << 16) | ((q3 & 255) << 24);
  }
  *(i32x4*)(x8 + (size_t)t * NIN_C + tid * 16) = o;
}

// ---------------- pass 1b: repack qweight (int32 codes) -> i8 (q-8) ----------
__global__ __launch_bounds__(256) void repack_w_kernel(
    const int* __restrict__ qw, char* __restrict__ w8)
{
  const size_t base = ((size_t)blockIdx.x * 256 + threadIdx.x) * 16;
  i32x4 o;
#pragma unroll
  for (int r = 0; r < 4; ++r) {
    i32x4 q = *(const i32x4*)(qw + base + r * 4);
    o[r] = ((q[0] - QZERO_C) & 255) | (((q[1] - QZERO_C) & 255) << 8) |
           (((q[2] - QZERO_C) & 255) << 16) | (((q[3] - QZERO_C) & 255) << 24);
  }
  *(i32x4*)(w8 + base) = o;
}

// ---------------- pass 1c: transpose scales [NOUT][32] -> sT[32][NOUT] -------
__global__ __launch_bounds__(256) void tsc_kernel(
    const float* __restrict__ sc, float* __restrict__ sT)
{
  const int id = blockIdx.x * 256 + threadIdx.x;   // over 32*4096
  const int o = id & (NOUT_C - 1), g = id >> 12;
  sT[id] = sc[o * (NIN_C / GROUP_C) + g];
}

// ---------------- pass 2: i8 GEMM ---------------------------------------------
// R12 with ONE structural change from its counters: LDS 128KB -> 64KB
// (ring-4 -> dbuf-2) so TWO 1024-thread blocks co-reside per CU -> 8 waves/
// SIMD (R12: 1 block/CU, 4 waves/SIMD, Occupancy 45.9%, latency-bound with
// every pipe <25% busy). Stage tile t+1 during t into the slot t-1 vacated;
// tile-end WAITV(0)+barrier — the co-resident block computes through our
// drain, so TLP replaces the counted-vmcnt trick. setprio dropped (m190:
// null on lockstep GEMM). Swizzle + fenced transposed epilogue kept (R12:
// conflicts 1.68e7 -> 1.05e6, absmax 0.211 verified).
#define BM 256
#define BN 256
#define BKB 64
#define NT (NIN_C / BKB)           // 64 tiles

__global__ __launch_bounds__(1024) void gemm_i8_kernel(
    const char* __restrict__ Ag,   // x8 [M][K] i8
    const char* __restrict__ Bg,   // w8 [N][K] i8
    const float* __restrict__ sTg, // [32][NOUT]
    const float* __restrict__ sx,  // [M]
    float* __restrict__ C)         // [M][N] f32
{
  constexpr int N = NOUT_C, KB = NIN_C;
  // slot s (0/1): A at s*32768, B at s*32768+16384
  __shared__ char smem[65536];

  const int tid  = threadIdx.x;
  const int lane = tid & 63;
  const int wid  = tid >> 6;       // 0..15
  const int wm   = wid >> 2;       // 0..3 -> 64 rows of C
  const int wn   = wid & 3;        // 0..3 -> 64 cols of C
  const int bm   = blockIdx.x;
  const int bn   = blockIdx.y;

  const int frow  = lane & 15;
  const int klane = lane >> 4;     // 0..3

  // staging: thread -> LDS row tid>>2, granule tid&3 (dest LINEAR);
  // source granule pre-swizzled: (tid&3) ^ ((tid>>3)&3)  [= g ^ ((row>>1)&3)]
  const int gsrc = ((tid & 3) ^ ((tid >> 3) & 3)) * 16;
  const uint32_t aoff = (uint32_t)((bm * BM + (tid >> 2)) * KB + gsrc);
  const uint32_t boff = (uint32_t)((bn * BN + (tid >> 2)) * KB + gsrc);
  const int sdst = tid * 16;

#define STG(tt, SW) { char* d_ = smem + (SW) * 32768 + sdst;                   \
    gload16(Ag + aoff + (uint32_t)(tt) * BKB, d_);                             \
    gload16(Bg + boff + (uint32_t)(tt) * BKB, d_ + 16384); }

  const int ccol0 = bn * BN + wn * 64;
  const int scoff = ccol0 + frow;
#define LD_S(dst, g)                                                           \
  _Pragma("unroll")                                                            \
  for (int j_ = 0; j_ < 4; ++j_)                                               \
    dst[j_] = sTg[(size_t)(g) * NOUT_C + scoff + j_ * 16];

  // fragment read bases with matching XOR swizzle (row%4 bits = frow%4)
  const int kswz = (klane ^ ((frow >> 1) & 3)) << 4;
  const int ard0 = (wm * 64 + frow) * 64 + kswz;           // + ii*1024
  const int brd0 = (wn * 64 + frow) * 64 + kswz + 16384;   // + j*1024

  f32x4 facc[4][4] = {};
  const i32x4 zq = {0, 0, 0, 0};

#define MFI(a_, b_, c_) __builtin_amdgcn_mfma_i32_16x16x64_i8(a_, b_, c_, 0, 0, 0)
#define APPLY(ii, jj, pv, scur)                                                \
  { f32x4 tf_;                                                                 \
    tf_[0] = (float)(pv)[0]; tf_[1] = (float)(pv)[1];                          \
    tf_[2] = (float)(pv)[2]; tf_[3] = (float)(pv)[3];                          \
    facc[ii][jj] += tf_ * (scur)[jj]; }
#define BAR __builtin_amdgcn_s_barrier()
#define WAITV(n) asm volatile("s_waitcnt vmcnt(" #n ")" ::: "memory")
#define SBAR0 __builtin_amdgcn_sched_barrier(0)

  // One tile: LD_S (when new group ahead) -> STG(t+1 into other slot) ->
  // 4 bf reads -> 4x{ak read, 4 MFMA, 4 apply} -> WAITV(0) -> barrier.
  // Slot (t+1)&1 was read in tile t-1, whose end barrier precedes this
  // stage issue -> race-free; stage lands before end-of-t barrier.
#define TILE(tt, SLOT, scur, DO_LDS, snxt, gnxt, DO_STG)                       \
  {                                                                            \
    const char* As_ = smem + (SLOT) * 32768;                                   \
    const char* Bs_ = smem + (SLOT) * 32768;                                   \
    if (DO_LDS) { LD_S(snxt, gnxt); }                                          \
    if (DO_STG) { STG((tt) + 1, (SLOT) ^ 1); }                                 \
    i32x4 bf0 = *(const i32x4*)(Bs_ + brd0);                                   \
    i32x4 bf1 = *(const i32x4*)(Bs_ + brd0 + 1024);                            \
    i32x4 bf2 = *(const i32x4*)(Bs_ + brd0 + 2048);                            \
    i32x4 bf3 = *(const i32x4*)(Bs_ + brd0 + 3072);                            \
    _Pragma("unroll")                                                          \
    for (int ii = 0; ii < 4; ++ii) {                                           \
      i32x4 ak = *(const i32x4*)(As_ + ard0 + ii * 1024);                      \
      i32x4 p0, p1, p2, p3;                                                    \
      p0 = MFI(ak, bf0, zq); p1 = MFI(ak, bf1, zq);                            \
      p2 = MFI(ak, bf2, zq); p3 = MFI(ak, bf3, zq);                            \
      APPLY(ii, 0, p0, scur); APPLY(ii, 1, p1, scur);                          \
      APPLY(ii, 2, p2, scur); APPLY(ii, 3, p3, scur);                          \
    }                                                                          \
    WAITV(0); SBAR0; BAR;                                                      \
  }

  float sA[4], sB[4];

  // ---- prologue: s(0) + tile 0 into slot 0, drain ----
  LD_S(sA, 0);
  STG(0, 0);
  WAITV(0);
  BAR; SBAR0;

  // ---- main loop: 4 tiles/iter; tile t uses slot t&1, group t>>1.
  // Entering iter t0: sA = s(g0). Load sB=s(g0+1) @ t0, sA=s(g0+2) @ t0+2.
  for (int t0 = 0; t0 < 56; t0 += 4) {
    const int g0 = t0 >> 1;
    TILE(t0,     0, sA, 1, sB, g0 + 1, 1);
    TILE(t0 + 1, 1, sA, 0, sB, 0,      1);
    TILE(t0 + 2, 0, sB, 1, sA, g0 + 2, 1);
    TILE(t0 + 3, 1, sB, 0, sA, 0,      1);
  }
  // ---- peel tiles 56..63 (groups 28..31; sA holds s28 entering) ----
  TILE(56, 0, sA, 1, sB, 29, 1);
  TILE(57, 1, sA, 0, sB, 0,  1);
  TILE(58, 0, sB, 1, sA, 30, 1);
  TILE(59, 1, sB, 0, sA, 0,  1);
  TILE(60, 0, sA, 1, sB, 31, 1);
  TILE(61, 1, sA, 0, sB, 0,  1);
  TILE(62, 0, sB, 0, sA, 0,  1);   // stages tile 63 (last)
  TILE(63, 1, sB, 0, sA, 0,  0);   // final barrier guards epilogue smem reuse

  // ---- epilogue: transposed through LDS (smem free after final barrier).
  // Per fi: wave scatters its 16x64 f32 block (sx applied) into a private
  // 4KB region, __syncthreads (fence: orders mixed-type LDS RAW — R11's
  // missing fence was the bug), reads back row-major, stores 256B-contiguous
  // runs; trailing sync guards WAR with next fi's scatter.
  const int crow0 = bm * BM + wm * 64;
  const int r0 = klane << 2;
  char* const wb = smem + wid * 4096;   // 16 waves x 4KB = 64KB
#pragma unroll
  for (int fi = 0; fi < 4; ++fi) {
    const f32x4 sxv = *(const f32x4*)(sx + crow0 + fi * 16 + r0);
#pragma unroll
    for (int j = 0; j < 4; ++j) {
      f32x4 v = facc[fi][j];
#pragma unroll
      for (int r = 0; r < 4; ++r)
        *(float*)(wb + (r0 + r) * 256 + (j * 16 + frow) * 4) = v[r] * sxv[r];
    }
    __syncthreads();
#pragma unroll
    for (int sub = 0; sub < 4; ++sub) {
      const int row16 = klane + sub * 4;
      f32x4 v = *(const f32x4*)(wb + row16 * 256 + frow * 16);
      *(f32x4*)(C + (int64_t)(crow0 + fi * 16 + row16) * N + ccol0 + frow * 4) = v;
    }
    __syncthreads();
  }
#undef STG
#undef LD_S
#undef MFI
#undef APPLY
#undef TILE
#undef BAR
#undef WAITV
#undef SBAR0
}

// ---------------- fallback (only if ws too small): naive fp32 ---------------
__global__ __launch_bounds__(256) void naive_kernel(
    const float* __restrict__ x, const int* __restrict__ qw,
    const float* __restrict__ sc, float* __restrict__ out)
{
  const int64_t idx = (int64_t)blockIdx.x * 256 + threadIdx.x;
  const int tok = (int)(idx >> 12);
  const int o   = (int)(idx & 4095);
  const float* xr = x + (int64_t)tok * NIN_C;
  const int* qr = qw + (int64_t)o * NIN_C;
  float acc = 0.f;
  for (int g = 0; g < NIN_C / GROUP_C; ++g) {
    float s = sc[(o << 5) | g];
    float ga = 0.f;
#pragma unroll 4
    for (int i = g * GROUP_C; i < (g + 1) * GROUP_C; ++i)
      ga += xr[i] * (float)(qr[i] - QZERO_C);
    acc += s * ga;
  }
  out[idx] = acc;
}

extern "C" void kernel_launch(void* const* d_in, const int* in_sizes, int n_in,
                              void* d_out, int out_size, void* d_ws, size_t ws_size,
                              hipStream_t stream) {
  const float* x  = (const float*)d_in[0];
  const int*   qw = (const int*)d_in[1];
  const float* sc = (const float*)d_in[2];
  float* out = (float*)d_out;

  const size_t x8_bytes = (size_t)TOKENS_C * NIN_C;          // 32 MiB
  const size_t w8_bytes = (size_t)NOUT_C * NIN_C;            // 16 MiB
  const size_t sx_bytes = (size_t)TOKENS_C * sizeof(float);  // 32 KiB
  const size_t sT_bytes = (size_t)(NIN_C / GROUP_C) * NOUT_C * sizeof(float);

  if (ws_size < x8_bytes + w8_bytes + sx_bytes + sT_bytes) {
    const int64_t total = (int64_t)TOKENS_C * NOUT_C;
    naive_kernel<<<(int)(total / 256), 256, 0, stream>>>(x, qw, sc, out);
    return;
  }

  char*  x8 = (char*)d_ws;
  char*  w8 = (char*)d_ws + x8_bytes;
  float* sx = (float*)((char*)d_ws + x8_bytes + w8_bytes);
  float* sT = (float*)((char*)d_ws + x8_bytes + w8_bytes + sx_bytes);

  quant_x_kernel<<<TOKENS_C, 256, 0, stream>>>(x, x8, sx);
  repack_w_kernel<<<(int)(w8_bytes / 16 / 256), 256, 0, stream>>>(qw, w8);
  tsc_kernel<<<(int)((NIN_C / GROUP_C) * NOUT_C / 256), 256, 0, stream>>>(sc, sT);
  {
    dim3 grid(TOKENS_C / BM, NOUT_C / BN);   // 32 x 16 = 512 wg
    gemm_i8_kernel<<<grid, 1024, 0, stream>>>(x8, w8, sT, sx, out);
  }
}